// Round 1
// baseline (98.601 us; speedup 1.0000x reference)
//
#include <hip/hip_runtime.h>

#define B_ 4
#define S_ 4096
#define H_ 16
#define D_ 1024
#define HD_ 64
#define NC_ 8
#define CH_ (S_ / NC_)   // 512 rows per phase-1 block

// (tanh(x)+1)/2 == sigmoid(2x) == 1/(1+exp2(-2x*log2(e)))
__device__ __forceinline__ float featmap(float x) {
  float e = __expf(-2.0f * x);                  // v_exp_f32 based, ~2ulp
  return __builtin_amdgcn_rcpf(1.0f + e);       // v_rcp_f32, ~1ulp
}

// ---------------- Phase 1: partial KV (64x64) + partial ksum per (b,h,chunk)
__global__ __launch_bounds__(256, 2) void mh_p1(
    const float* __restrict__ kg, const float* __restrict__ vg,
    float* __restrict__ kvp, float* __restrict__ kredp) {
  __shared__ float kt[64][64];
  __shared__ float vt[64][64];
  __shared__ float ksr[4][64];

  const int bid = blockIdx.x;       // 0..511
  const int bh  = bid & 63;         // b*16+h
  const int c   = bid >> 6;         // chunk 0..NC_-1
  const int b   = bh >> 4, h = bh & 15;
  const int t    = threadIdx.x;
  const int w    = t >> 6;          // wave 0..3
  const int lane = t & 63;
  const int dg = lane >> 3, eg = lane & 7;
  const int d0 = dg * 8, e0 = eg * 8;

  const size_t rowbase = (size_t)b * S_ * D_ + (size_t)h * HD_;
  const float* kb = kg + rowbase;
  const float* vb = vg + rowbase;
  const int s0 = c * CH_;

  float acc[8][8];
#pragma unroll
  for (int i = 0; i < 8; ++i)
#pragma unroll
    for (int j = 0; j < 8; ++j) acc[i][j] = 0.f;
  float ks = 0.f;  // partial column-sum of sigmoid(k), column = lane

#pragma unroll 1
  for (int tile = 0; tile < CH_ / 64; ++tile) {
    const int rb = s0 + tile * 64 + w * 16;
    // stage: wave w owns rows [w*16, w*16+16) -> no cross-wave hazard, no barrier
#pragma unroll
    for (int i = 0; i < 16; ++i) {
      const size_t g = (size_t)(rb + i) * D_ + lane;
      float kh = featmap(kb[g]);
      float vv = vb[g];
      kt[w * 16 + i][lane] = kh;
      vt[w * 16 + i][lane] = vv;
      ks += kh;
    }
    // accumulate outer products from own rows
#pragma unroll
    for (int i = 0; i < 16; ++i) {
      const int r = w * 16 + i;
      float4 k0 = *(const float4*)&kt[r][d0];
      float4 k1 = *(const float4*)&kt[r][d0 + 4];
      float4 v0 = *(const float4*)&vt[r][e0];
      float4 v1 = *(const float4*)&vt[r][e0 + 4];
      float kd[8] = {k0.x, k0.y, k0.z, k0.w, k1.x, k1.y, k1.z, k1.w};
      float ve[8] = {v0.x, v0.y, v0.z, v0.w, v1.x, v1.y, v1.z, v1.w};
#pragma unroll
      for (int di = 0; di < 8; ++di)
#pragma unroll
        for (int ej = 0; ej < 8; ++ej) acc[di][ej] += kd[di] * ve[ej];
    }
  }

  // ---- reduce 4 wave replicas (tree through LDS), no atomics
  ksr[w][lane] = ks;
  __syncthreads();
  float* ktf = &kt[0][0];
  float* vtf = &vt[0][0];
  if (w >= 2) {
    float* dst = (w == 2) ? ktf : vtf;
#pragma unroll
    for (int di = 0; di < 8; ++di) {
      float4 a = {acc[di][0], acc[di][1], acc[di][2], acc[di][3]};
      float4 bq = {acc[di][4], acc[di][5], acc[di][6], acc[di][7]};
      *(float4*)&dst[(d0 + di) * 64 + e0] = a;
      *(float4*)&dst[(d0 + di) * 64 + e0 + 4] = bq;
    }
  }
  __syncthreads();
  if (w < 2) {
    const float* src = (w == 0) ? ktf : vtf;
#pragma unroll
    for (int di = 0; di < 8; ++di)
#pragma unroll
      for (int ej = 0; ej < 8; ++ej) acc[di][ej] += src[(d0 + di) * 64 + e0 + ej];
  }
  __syncthreads();
  if (w == 1) {
#pragma unroll
    for (int di = 0; di < 8; ++di) {
      float4 a = {acc[di][0], acc[di][1], acc[di][2], acc[di][3]};
      float4 bq = {acc[di][4], acc[di][5], acc[di][6], acc[di][7]};
      *(float4*)&ktf[(d0 + di) * 64 + e0] = a;
      *(float4*)&ktf[(d0 + di) * 64 + e0 + 4] = bq;
    }
  }
  __syncthreads();
  if (w == 0) {
    float* dst = kvp + ((size_t)(c * 64 + bh)) * 4096;
#pragma unroll
    for (int di = 0; di < 8; ++di) {
#pragma unroll
      for (int ej = 0; ej < 8; ++ej) acc[di][ej] += ktf[(d0 + di) * 64 + e0 + ej];
      float4 a = {acc[di][0], acc[di][1], acc[di][2], acc[di][3]};
      float4 bq = {acc[di][4], acc[di][5], acc[di][6], acc[di][7]};
      *(float4*)&dst[(d0 + di) * 64 + e0] = a;
      *(float4*)&dst[(d0 + di) * 64 + e0 + 4] = bq;
    }
  }
  if (t < 64) {
    float tot = ksr[0][t] + ksr[1][t] + ksr[2][t] + ksr[3][t];
    kredp[(size_t)(c * 64 + bh) * 64 + t] = tot;
  }
}

// ---------------- Phase 1.5: reduce chunk partials -> kv, kred
__global__ __launch_bounds__(256) void mh_p15(
    const float* __restrict__ kvp, const float* __restrict__ kredp,
    float* __restrict__ kv, float* __restrict__ kred) {
  const int i = blockIdx.x * 256 + threadIdx.x;  // 0..262143
  float s = 0.f;
#pragma unroll
  for (int c = 0; c < NC_; ++c) s += kvp[(size_t)c * (64 * 4096) + i];
  kv[i] = s;
  if (i < 64 * 64) {
    float r = 0.f;
#pragma unroll
    for (int c = 0; c < NC_; ++c) r += kredp[c * 4096 + i];
    kred[i] = r + 1e-8f;
  }
}

// ---------------- Phase 2: out = z * qh @ KV ; lane owns one s-row
__global__ __launch_bounds__(256, 2) void mh_p2(
    const float* __restrict__ qg, const float* __restrict__ kv,
    const float* __restrict__ kred, float* __restrict__ outg) {
  const int bid = blockIdx.x;  // 0..1023
  const int bh = bid >> 4;
  const int sc = bid & 15;
  const int b = bh >> 4, h = bh & 15;
  const int t = threadIdx.x;
  const int w = t >> 6, lane = t & 63;
  const int s = sc * 256 + w * 64 + lane;

  const float* qrow = qg + (size_t)(b * S_ + s) * D_ + h * HD_;
  const float* kvb = kv + (size_t)bh * 4096;   // wave-uniform
  const float* krd = kred + bh * 64;           // wave-uniform

  float acc[64];
#pragma unroll
  for (int e = 0; e < 64; ++e) acc[e] = 0.f;
  float zacc = 0.f;

#pragma unroll 2
  for (int d4 = 0; d4 < 16; ++d4) {
    float4 qv = *(const float4*)(qrow + d4 * 4);
    float qh0 = featmap(qv.x), qh1 = featmap(qv.y);
    float qh2 = featmap(qv.z), qh3 = featmap(qv.w);
    float qh[4] = {qh0, qh1, qh2, qh3};
#pragma unroll
    for (int j = 0; j < 4; ++j) {
      const int d = d4 * 4 + j;
      zacc += qh[j] * krd[d];
      const float* row = kvb + d * 64;  // uniform address -> s_load expected
#pragma unroll
      for (int e = 0; e < 64; ++e) acc[e] += qh[j] * row[e];
    }
  }

  const float z = 1.0f / zacc;
  float* orow = outg + (size_t)(b * S_ + s) * D_ + h * HD_;
#pragma unroll
  for (int e4 = 0; e4 < 16; ++e4) {
    float4 o = {acc[e4 * 4] * z, acc[e4 * 4 + 1] * z,
                acc[e4 * 4 + 2] * z, acc[e4 * 4 + 3] * z};
    *(float4*)(orow + e4 * 4) = o;
  }
}

extern "C" void kernel_launch(void* const* d_in, const int* in_sizes, int n_in,
                              void* d_out, int out_size, void* d_ws, size_t ws_size,
                              hipStream_t stream) {
  const float* q = (const float*)d_in[0];
  const float* k = (const float*)d_in[1];
  const float* v = (const float*)d_in[2];
  float* out = (float*)d_out;
  float* ws = (float*)d_ws;

  float* kv    = ws;                           // 262144 floats (1 MiB)
  float* kred  = ws + 262144;                  // 4096 floats
  float* kvp   = ws + 262144 + 4096;           // NC_*262144 floats (8 MiB)
  float* kredp = kvp + (size_t)NC_ * 262144;   // NC_*4096 floats

  mh_p1 <<<64 * NC_, 256, 0, stream>>>(k, v, kvp, kredp);
  mh_p15<<<1024,     256, 0, stream>>>(kvp, kredp, kv, kred);
  mh_p2 <<<64 * 16,  256, 0, stream>>>(q, kv, kred, out);
}